// Round 4
// baseline (142.626 us; speedup 1.0000x reference)
//
#include <hip/hip_runtime.h>
#include <cstdint>

// Chamfer distance, B=8, N=M=4096, D=128, f32 in, scalar f32 out.
// R16: fusion WITHOUT grid.sync (R15's cooperative attempt returned out=0:
// either launch rejected or cross-XCD visibility -- both avoided by making
// all producer/consumer intra-block). pass1 is folded into the tile kernel:
// each block converts its x-panel (8x redundant) and y-tiles (16x redundant)
// f32->bf16 on the fly; x2/y2 computed inline (y2 into dbuf LDS ys2[2][64]).
// y staging is reg-staged (T14): 2 batches of 4 float4/thread (16 VGPR in
// flight), issued at iter top / after ct1, cvt+ds_write (same XOR swizzle)
// after ct1 / ct3. ct clusters back to R12-style interleaved bfr reads (no
// hoist, no setprio -- both implicated in R14's 46.7->53.2 regression).
// Col-min: 1x shfl_xor(16) -> cminW[2][8][64] (4KB). LDS 37376B -> 4 blk/CU.
// Dispatches: memset + tile_fused + pass3 (was memset + 3 kernels).
// Workspace: rowpart(1M) colpart(2M) only.

#define B_   8
#define N_   4096
#define M_   4096
#define D_   128
#define TPB  8               // y-tiles (64 cols) per block -> 512-col chunk
#define ROWS_PB 256          // x-rows per block = 4 waves * 64
#define XG   (N_ / ROWS_PB)  // 16 x-groups
#define CHUNKS (M_ / (TPB * 64))   // 8 y-chunks
#define GRID (B_ * XG * CHUNKS)    // 1024 blocks

typedef __bf16 bf16x8 __attribute__((ext_vector_type(8)));
typedef float  f32x4  __attribute__((ext_vector_type(4)));
typedef unsigned int u32;

static __device__ __forceinline__ unsigned short f2bf(float f) {
  unsigned u = __float_as_uint(f);
  u += 0x7FFFu + ((u >> 16) & 1u);   // round-to-nearest-even
  return (unsigned short)(u >> 16);
}
static __device__ __forceinline__ u32 pk2(float a, float b) {
  return (u32)f2bf(a) | ((u32)f2bf(b) << 16);
}

// Fragment layouts (HW-verified):
//   A/B operand: lane holds elems [row=lane&15][k=(lane>>4)*8 + 0..7]
//   C/D:         lane reg r holds [row=(lane>>4)*4+r][col=lane&15]
// acc init = x2_i (afrag holds bf16(-2x)), so a = x2_i - 2<x,y>; s = a + y2_j.
// LDS y layout: row r (256B), logical 16B-chunk c at physical chunk c^(r&15).

#define DO_CT(CT)                                                              \
  {                                                                            \
    f32x4 a[4];                                                                \
    _Pragma("unroll")                                                          \
    for (int rt = 0; rt < 4; ++rt) a[rt] = xvv[rt];                            \
    _Pragma("unroll")                                                          \
    for (int kb = 0; kb < 4; ++kb) {                                           \
      const int row = (CT) * 16 + l15;                                         \
      const int pcB = (kb * 4 + quad) ^ l15;                                   \
      bf16x8 bfr = *(const bf16x8*)((const char*)ys + d + row * 256 + pcB * 16); \
      _Pragma("unroll")                                                        \
      for (int rt = 0; rt < 4; ++rt)                                           \
        a[rt] = __builtin_amdgcn_mfma_f32_16x16x32_bf16(afrag[kb][rt], bfr, a[rt], 0, 0, 0); \
    }                                                                          \
    float yv = y2r[(CT)];                                                      \
    float cm = FINF;                                                           \
    _Pragma("unroll")                                                          \
    for (int rt = 0; rt < 4; ++rt) {                                           \
      _Pragma("unroll")                                                        \
      for (int r = 0; r < 4; ++r) {                                            \
        float s = a[rt][r] + yv;                                               \
        rmin2[rt][r] = fminf(rmin2[rt][r], s);                                 \
        cm = fminf(cm, s);                                                     \
      }                                                                        \
    }                                                                          \
    cm = fminf(cm, __shfl_xor(cm, 16, 64));  /* fold quad pairs */             \
    if ((quad & 1) == 0)                                                       \
      cminW[t & 1][wave * 2 + (quad >> 1)][(CT) * 16 + l15] = cm;              \
  }

__global__ __launch_bounds__(256) void tile_fused(
    const float* __restrict__ x, const float* __restrict__ y,
    float* __restrict__ rowpart, float* __restrict__ colpart)
{
  __shared__ unsigned short ys[2 * 8192];    // two 16 KB swizzled y-tiles
  __shared__ float ys2[2][64];               // dbuf per-tile y^2 (512 B)
  __shared__ float cminW[2][8][64];          // dbuf per-(wave,qpair) col-min (4 KB)

  const int tid  = threadIdx.x;
  const int wave = tid >> 6;                 // 0..3
  const int lane = tid & 63;
  const int quad = lane >> 4;
  const int l15  = lane & 15;
  const int r0   = tid >> 2;                 // y staging: row 0..63
  const int qp   = tid & 3;                  // quarter-row (32 floats)

  const int id    = blockIdx.x;        // 0..1023
  const int b     = id & 7;
  const int xg    = (id >> 3) & 15;
  const int chunk = id >> 7;           // 0..7
  const int n0    = xg * ROWS_PB;
  const int mc0   = chunk * (TPB * 64);

  // ---- prologue A: stage y tile 0 (f32 -> bf16 swizzled LDS + y2) ----
  {
    const float* ysrc = y + (size_t)(b * M_ + mc0 + r0) * D_ + qp * 32;
    float4 v0[8];
    #pragma unroll
    for (int i = 0; i < 8; ++i) v0[i] = *(const float4*)(ysrc + i * 4);
    float p = 0.0f;
    #pragma unroll
    for (int i = 0; i < 8; ++i)
      p += v0[i].x*v0[i].x + v0[i].y*v0[i].y + v0[i].z*v0[i].z + v0[i].w*v0[i].w;
    p += __shfl_xor(p, 1, 64);
    p += __shfl_xor(p, 2, 64);       // sum over the 4 quarter-row lanes
    if ((lane & 3) == 0) ys2[0][r0] = p;
    #pragma unroll
    for (int j = 0; j < 4; ++j) {    // logical chunk qp*4+j -> swizzled
      int pc = (qp * 4 + j) ^ (r0 & 15);
      uint4 w;
      w.x = pk2(v0[2*j].x,   v0[2*j].y);
      w.y = pk2(v0[2*j].z,   v0[2*j].w);
      w.z = pk2(v0[2*j+1].x, v0[2*j+1].y);
      w.w = pk2(v0[2*j+1].z, v0[2*j+1].w);
      *(uint4*)((char*)ys + r0 * 256 + pc * 16) = w;
    }
  }

  // ---- prologue B: x panel f32 -> afrag(bf16 of -2x) + x2 via quad folds ----
  bf16x8 afrag[4][4];   // [kb][rt]
  f32x4 xvv[4];
  {
    float x2row[4];
    #pragma unroll
    for (int rt = 0; rt < 4; ++rt) {
      const float* xs = x + (size_t)(b * N_ + n0 + wave * 64 + rt * 16 + l15) * D_ + quad * 8;
      float p = 0.0f;
      #pragma unroll
      for (int kb = 0; kb < 4; ++kb) {
        float4 u0 = *(const float4*)(xs + kb * 32);
        float4 u1 = *(const float4*)(xs + kb * 32 + 4);
        p += u0.x*u0.x + u0.y*u0.y + u0.z*u0.z + u0.w*u0.w
           + u1.x*u1.x + u1.y*u1.y + u1.z*u1.z + u1.w*u1.w;
        union { u32 w[4]; bf16x8 v; } tt;
        tt.w[0] = pk2(-2.f*u0.x, -2.f*u0.y);
        tt.w[1] = pk2(-2.f*u0.z, -2.f*u0.w);
        tt.w[2] = pk2(-2.f*u1.x, -2.f*u1.y);
        tt.w[3] = pk2(-2.f*u1.z, -2.f*u1.w);
        afrag[kb][rt] = tt.v;
      }
      p += __shfl_xor(p, 16, 64);    // fold the 4 quads holding this row
      p += __shfl_xor(p, 32, 64);
      x2row[rt] = p;                 // = x2 of row rt*16 + l15
    }
    // redistribute to C/D layout: lane needs rows quad*4 + r
    #pragma unroll
    for (int rt = 0; rt < 4; ++rt)
      #pragma unroll
      for (int r = 0; r < 4; ++r)
        xvv[rt][r] = __shfl(x2row[rt], quad * 4 + r, 16);
  }

  const float FINF = __uint_as_float(0x7F800000u);
  float rmin2[4][4];
  #pragma unroll
  for (int rt = 0; rt < 4; ++rt)
    #pragma unroll
    for (int r = 0; r < 4; ++r) rmin2[rt][r] = FINF;

  __syncthreads();   // tile 0 + ys2[0] staged

  #pragma unroll 1
  for (int t = 0; t < TPB; ++t) {
    const int m0 = mc0 + t * 64;
    const int d  = (t & 1) * 16384;    // current buffer byte offset
    const int dn = 16384 - d;          // next buffer byte offset
    const bool pf = (t + 1 < TPB);
    const float* nsrc = y + (size_t)(b * M_ + m0 + 64 + r0) * D_ + qp * 32;

    // issue staging batch A for tile t+1 (16 floats; 16 VGPR in flight)
    float4 sv[4];
    if (pf) {
      #pragma unroll
      for (int i = 0; i < 4; ++i) sv[i] = *(const float4*)(nsrc + i * 4);
    }

    // flush previous tile's column mins (other cminW buffer -> no race)
    if (t > 0 && tid < 64) {
      const float* cb = &cminW[(t - 1) & 1][0][0];
      float v = cb[tid];
      #pragma unroll
      for (int w = 1; w < 8; ++w) v = fminf(v, cb[w * 64 + tid]);
      colpart[(size_t)xg * (B_ * M_) + (size_t)b * M_ + (m0 - 64) + tid] = v;
    }

    // per-tile y^2 from LDS (written during t-1's staging; broadcast reads)
    float y2r[4];
    #pragma unroll
    for (int ct = 0; ct < 4; ++ct) y2r[ct] = ys2[t & 1][ct * 16 + l15];

    float y2p = 0.0f;

    DO_CT(0)
    DO_CT(1)

    if (pf) {   // consume batch A (chunks 0,1 of each quarter-row), issue B
      #pragma unroll
      for (int i = 0; i < 4; ++i)
        y2p += sv[i].x*sv[i].x + sv[i].y*sv[i].y + sv[i].z*sv[i].z + sv[i].w*sv[i].w;
      #pragma unroll
      for (int j = 0; j < 2; ++j) {
        int pc = (qp * 4 + j) ^ (r0 & 15);
        uint4 w;
        w.x = pk2(sv[2*j].x,   sv[2*j].y);
        w.y = pk2(sv[2*j].z,   sv[2*j].w);
        w.z = pk2(sv[2*j+1].x, sv[2*j+1].y);
        w.w = pk2(sv[2*j+1].z, sv[2*j+1].w);
        *(uint4*)((char*)ys + dn + r0 * 256 + pc * 16) = w;
      }
      #pragma unroll
      for (int i = 0; i < 4; ++i) sv[i] = *(const float4*)(nsrc + 16 + i * 4);
    }

    DO_CT(2)
    DO_CT(3)

    if (pf) {   // consume batch B (chunks 2,3) + finalize y2 for tile t+1
      #pragma unroll
      for (int i = 0; i < 4; ++i)
        y2p += sv[i].x*sv[i].x + sv[i].y*sv[i].y + sv[i].z*sv[i].z + sv[i].w*sv[i].w;
      #pragma unroll
      for (int j = 2; j < 4; ++j) {
        int pc = (qp * 4 + j) ^ (r0 & 15);
        int i0 = 2 * (j - 2);
        uint4 w;
        w.x = pk2(sv[i0].x,   sv[i0].y);
        w.y = pk2(sv[i0].z,   sv[i0].w);
        w.z = pk2(sv[i0+1].x, sv[i0+1].y);
        w.w = pk2(sv[i0+1].z, sv[i0+1].w);
        *(uint4*)((char*)ys + dn + r0 * 256 + pc * 16) = w;
      }
      y2p += __shfl_xor(y2p, 1, 64);
      y2p += __shfl_xor(y2p, 2, 64);
      if ((lane & 3) == 0) ys2[(t + 1) & 1][r0] = y2p;
    }

    __syncthreads();  // buf nxt + ys2 nxt complete; cminW[t&1] visible
  }

  // final tile's column mins (cminW[(TPB-1)&1], fenced by last barrier)
  if (tid < 64) {
    const float* cb = &cminW[(TPB - 1) & 1][0][0];
    float v = cb[tid];
    #pragma unroll
    for (int w = 1; w < 8; ++w) v = fminf(v, cb[w * 64 + tid]);
    colpart[(size_t)xg * (B_ * M_) + (size_t)b * M_ + (mc0 + (TPB - 1) * 64) + tid] = v;
  }

  // Row mins over this chunk: reduce across 16 col-lanes (once, at the end).
  #pragma unroll
  for (int rt = 0; rt < 4; ++rt) {
    #pragma unroll
    for (int r = 0; r < 4; ++r) {
      float v = rmin2[rt][r];
      v = fminf(v, __shfl_xor(v, 1, 64));
      v = fminf(v, __shfl_xor(v, 2, 64));
      v = fminf(v, __shfl_xor(v, 4, 64));
      v = fminf(v, __shfl_xor(v, 8, 64));
      if (l15 == 0)
        rowpart[(size_t)chunk * (B_ * N_) + (size_t)b * N_ + n0 + wave * 64 + rt * 16 + quad * 4 + r] = v;
    }
  }
}

// Pass 3: reduce partials (min over chunks/x-groups), sqrt, sum, atomicAdd
// the block's contribution to the final scalar (d_out pre-zeroed).
__global__ __launch_bounds__(256) void pass3_final(
    const float* __restrict__ rowpart, const float* __restrict__ colpart,
    float* __restrict__ out)
{
  const int BN = B_ * N_;
  float s1 = 0.0f, s2 = 0.0f;
  for (int i = blockIdx.x * 256 + threadIdx.x; i < BN; i += 64 * 256) {
    float r = rowpart[i];
    #pragma unroll
    for (int c = 1; c < CHUNKS; ++c) r = fminf(r, rowpart[c * BN + i]);
    s1 += sqrtf(fmaxf(r, 0.0f));
    float m = colpart[i];
    #pragma unroll
    for (int g = 1; g < XG; ++g) m = fminf(m, colpart[g * BN + i]);
    s2 += sqrtf(fmaxf(m, 0.0f));
  }
  float s = s1 + s2;
  #pragma unroll
  for (int m = 1; m < 64; m <<= 1) s += __shfl_xor(s, m, 64);
  __shared__ float r1[4];
  int wave = threadIdx.x >> 6, lane = threadIdx.x & 63;
  if (lane == 0) r1[wave] = s;
  __syncthreads();
  if (threadIdx.x == 0)
    atomicAdd(out, (r1[0] + r1[1] + r1[2] + r1[3]) / (float)(B_ * N_));
}

extern "C" void kernel_launch(void* const* d_in, const int* in_sizes, int n_in,
                              void* d_out, int out_size, void* d_ws, size_t ws_size,
                              hipStream_t stream)
{
  const float* x = (const float*)d_in[0];
  const float* y = (const float*)d_in[1];
  char* ws = (char*)d_ws;

  float* rowpart = (float*)(ws);                  // 8*B*N floats = 1 MB
  float* colpart = (float*)(ws + (1u << 20));     // 16*B*M floats = 2 MB
  float* outf = (float*)d_out;

  hipMemsetAsync(outf, 0, sizeof(float), stream);  // atomicAdd target

  tile_fused<<<GRID, 256, 0, stream>>>(x, y, rowpart, colpart);

  pass3_final<<<64, 256, 0, stream>>>(rowpart, colpart, outf);
}